// Round 1
// 193.699 us; speedup vs baseline: 1.0605x; 1.0605x over previous
//
#include <hip/hip_runtime.h>
#include <hip/hip_fp16.h>

// MPM P2G, fixed-capacity cell buckets with 16B quantized records.
//
// node[g] = sum over particles in cells {g-1,g}^3 of trilinear w * (m, m*v)
// cell/node id: z + x*128 + y*128*128   (reference get_hash, dim==3)
//
// Primary pipeline (ONE atomic pass, no hist, no scan):
//   K1 place : atomicAdd(cursor[cell]) -> slot; write 16B record
//              {fx,fy,fz as u16 fixed-point, m,vx,vy,vz as fp16}.
//              CAP=4 -> 64B bucket = one cache line per cell.
//   K2 gather: LDS-TILED (R4). One block = 8x8x8 node tile; stage the
//              9x9x9 covering cells' buckets into LDS once (cuts the 8x
//              redundant scattered L2 reads to 1.42x), then per-thread
//              register accumulate + one coalesced float4 store.
//              LDS word-plane layout (plane stride 736 = 23*32 words)
//              -> accumulate-phase bank = sc%32, ~2-way conflicts only.
//   K3 fixup : rare overflow particles (E ~ 300) exact fp32 atomic scatter.
// Fallback: R3 counting-sort pipeline (verified, needs 48MB), then naive.

#define GRID_DIM   128
#define NUM_CELLS  (GRID_DIM * GRID_DIM * GRID_DIM)   // 2,097,152
#define INV_CELL   64.0f
#define OVF_MAX    65536
#define SCAN_BLKS  2048

#define MAXCAP     4
#define NSC        729          // 9*9*9 staged cells per tile
#define PLANE      736          // word-plane stride (multiple of 32)

__device__ __forceinline__ int cell_id(int ix, int iy, int iz) {
    return iz + ix * GRID_DIM + iy * (GRID_DIM * GRID_DIM);
}

__device__ __forceinline__ unsigned int q16(float f) {
    int q = (int)(f * 65536.0f + 0.5f);
    return (unsigned int)min(q, 65535);
}
__device__ __forceinline__ unsigned int f2h(float f) {
    return (unsigned int)__half_as_ushort(__float2half(f));
}
__device__ __forceinline__ float h2f(unsigned int b) {
    return __half2float(__ushort_as_half((unsigned short)(b & 0xffffu)));
}

// ---- K1: bucket placement (single atomic pass) ----------------------------
__global__ __launch_bounds__(256) void bucket_place_kernel(
    const float* __restrict__ pos, const float* __restrict__ vel,
    const float* __restrict__ mass, unsigned int* __restrict__ cursors,
    uint4* __restrict__ buckets, int* __restrict__ ovf_cnt,
    int* __restrict__ ovf_list, int cap, int n)
{
    int i = blockIdx.x * 256 + threadIdx.x;
    if (i >= n) return;
    float rx = pos[3 * i + 0] * INV_CELL;
    float ry = pos[3 * i + 1] * INV_CELL;
    float rz = pos[3 * i + 2] * INV_CELL;
    float bx = floorf(rx), by = floorf(ry), bz = floorf(rz);
    float fx = rx - bx, fy = ry - by, fz = rz - bz;   // in [0,1)
    int ix = min(max((int)bx, 0), GRID_DIM - 1);
    int iy = min(max((int)by, 0), GRID_DIM - 1);
    int iz = min(max((int)bz, 0), GRID_DIM - 1);
    int c = cell_id(ix, iy, iz);
    unsigned int s = atomicAdd(&cursors[c], 1u);
    if (s < (unsigned int)cap) {
        uint4 r;
        r.x = q16(fx) | (q16(fy) << 16);
        r.y = q16(fz) | (f2h(mass[i]) << 16);
        r.z = f2h(vel[3 * i + 0]) | (f2h(vel[3 * i + 1]) << 16);
        r.w = f2h(vel[3 * i + 2]);
        buckets[c * cap + (int)s] = r;
    } else {
        int o = atomicAdd(ovf_cnt, 1);
        if (o < OVF_MAX) ovf_list[o] = i;
    }
}

// ---- K2: LDS-tiled node gather over buckets -------------------------------
// Block = 8x8x8 node tile (512 threads, 1 node/thread).
// Stage 9x9x9 cells' buckets into LDS word-planes, then accumulate.
__global__ __launch_bounds__(512) void bucket_gather_tiled_kernel(
    const uint4* __restrict__ buckets, const unsigned int* __restrict__ cursors,
    float4* __restrict__ out, int cap)
{
    __shared__ unsigned int cnt_s[NSC];
    __shared__ unsigned int rec_s[4 * MAXCAP * PLANE];   // 47.1 KB

    int tid = threadIdx.x;
    int bz = blockIdx.x & 15;
    int bx = (blockIdx.x >> 4) & 15;
    int by = blockIdx.x >> 8;
    int g0x = bx * 8, g0y = by * 8, g0z = bz * 8;

    // ---- stage: one staged-cell per thread-slot, z-fastest (9-cell runs) --
    for (int sc = tid; sc < NSC; sc += 512) {
        int lz = sc % 9;
        int t  = sc / 9;
        int lx = t % 9;
        int ly = t / 9;
        int cz = g0z - 1 + lz, cx = g0x - 1 + lx, cy = g0y - 1 + ly;
        unsigned int cnt = 0;
        if (((unsigned)cz < (unsigned)GRID_DIM) &
            ((unsigned)cx < (unsigned)GRID_DIM) &
            ((unsigned)cy < (unsigned)GRID_DIM)) {
            int c = cell_id(cx, cy, cz);
            cnt = min(cursors[c], (unsigned)cap);
            int base = c * cap;
            for (int j = 0; j < (int)cnt; ++j) {
                uint4 r = buckets[base + j];
                rec_s[(0 * MAXCAP + j) * PLANE + sc] = r.x;
                rec_s[(1 * MAXCAP + j) * PLANE + sc] = r.y;
                rec_s[(2 * MAXCAP + j) * PLANE + sc] = r.z;
                rec_s[(3 * MAXCAP + j) * PLANE + sc] = r.w;
            }
        }
        cnt_s[sc] = cnt;
    }
    __syncthreads();

    // ---- accumulate: thread owns node (tx,ty,tz) in the tile --------------
    int tz = tid & 7, tx = (tid >> 3) & 7, ty = tid >> 6;
    float a0 = 0.0f, a1 = 0.0f, a2 = 0.0f, a3 = 0.0f;

    #pragma unroll
    for (int dy = 0; dy < 2; ++dy) {
        #pragma unroll
        for (int dx = 0; dx < 2; ++dx) {
            int scb = (ty + dy) * 81 + (tx + dx) * 9 + tz;
            #pragma unroll
            for (int dz = 0; dz < 2; ++dz) {
                int sc = scb + dz;
                int cnt = (int)cnt_s[sc];
                for (int j = 0; j < cnt; ++j) {
                    unsigned r0 = rec_s[(0 * MAXCAP + j) * PLANE + sc];
                    unsigned r1 = rec_s[(1 * MAXCAP + j) * PLANE + sc];
                    unsigned r2 = rec_s[(2 * MAXCAP + j) * PLANE + sc];
                    unsigned r3 = rec_s[(3 * MAXCAP + j) * PLANE + sc];
                    float fx = (float)(r0 & 0xffffu) * (1.0f / 65536.0f);
                    float fy = (float)(r0 >> 16)     * (1.0f / 65536.0f);
                    float fz = (float)(r1 & 0xffffu) * (1.0f / 65536.0f);
                    // dx==1 -> staged cell == node's own cell -> (1-frac)
                    float wx = dx ? (1.0f - fx) : fx;
                    float wy = dy ? (1.0f - fy) : fy;
                    float wz = dz ? (1.0f - fz) : fz;
                    float sm = wx * wy * wz * h2f(r1 >> 16);
                    a0 += sm;
                    a1 += sm * h2f(r2);
                    a2 += sm * h2f(r2 >> 16);
                    a3 += sm * h2f(r3);
                }
            }
        }
    }
    int id = (g0z + tz) + (g0x + tx) * GRID_DIM
           + (g0y + ty) * (GRID_DIM * GRID_DIM);
    out[id] = make_float4(a0, a1, a2, a3);
}

// ---- K3: overflow fixup (exact fp32, rare) --------------------------------
__global__ __launch_bounds__(256) void fixup_kernel(
    const float* __restrict__ pos, const float* __restrict__ vel,
    const float* __restrict__ mass, const int* __restrict__ ovf_cnt,
    const int* __restrict__ ovf_list, float* __restrict__ out)
{
    int total = min(*ovf_cnt, OVF_MAX);
    for (int k = blockIdx.x * 256 + threadIdx.x; k < total; k += gridDim.x * 256) {
        int i = ovf_list[k];
        float px = pos[3 * i + 0] * INV_CELL;
        float py = pos[3 * i + 1] * INV_CELL;
        float pz = pos[3 * i + 2] * INV_CELL;
        float bx = floorf(px), by = floorf(py), bz = floorf(pz);
        float fx = px - bx, fy = py - by, fz = pz - bz;
        int ix = (int)bx, iy = (int)by, iz = (int)bz;
        float m = mass[i];
        float vx = vel[3 * i + 0], vy = vel[3 * i + 1], vz = vel[3 * i + 2];
        float wx[2] = { 1.0f - fx, fx }, wy[2] = { 1.0f - fy, fy }, wz[2] = { 1.0f - fz, fz };
        #pragma unroll
        for (int a = 0; a < 2; ++a)
            #pragma unroll
            for (int b = 0; b < 2; ++b)
                #pragma unroll
                for (int c = 0; c < 2; ++c) {
                    int h = cell_id(ix + a, iy + b, iz + c);
                    bool valid = (h >= 0) && (h < NUM_CELLS);
                    int hc = min(max(h, 0), NUM_CELLS - 1);
                    float s = valid ? (wx[a] * wy[b] * wz[c]) : 0.0f;
                    float sm = s * m;
                    float* cell = out + 4 * (size_t)hc;
                    atomicAdd(cell + 0, sm);
                    atomicAdd(cell + 1, sm * vx);
                    atomicAdd(cell + 2, sm * vy);
                    atomicAdd(cell + 3, sm * vz);
                }
    }
}

// ======== fallback: R3 counting-sort pipeline (verified 228us) =============
__global__ __launch_bounds__(256) void s_hist_kernel(
    const float* __restrict__ pos, int* __restrict__ counts, int n)
{
    int i = blockIdx.x * 256 + threadIdx.x;
    if (i >= n) return;
    int ix = min(max((int)floorf(pos[3 * i + 0] * INV_CELL), 0), GRID_DIM - 1);
    int iy = min(max((int)floorf(pos[3 * i + 1] * INV_CELL), 0), GRID_DIM - 1);
    int iz = min(max((int)floorf(pos[3 * i + 2] * INV_CELL), 0), GRID_DIM - 1);
    atomicAdd(&counts[cell_id(ix, iy, iz)], 1);
}

__global__ __launch_bounds__(256) void s_scan_partials_kernel(
    const int* __restrict__ counts, int* __restrict__ partials)
{
    __shared__ int red[256];
    int t = threadIdx.x;
    int4 v = ((const int4*)counts)[blockIdx.x * 256 + t];
    red[t] = v.x + v.y + v.z + v.w;
    __syncthreads();
    for (int off = 128; off > 0; off >>= 1) {
        if (t < off) red[t] += red[t + off];
        __syncthreads();
    }
    if (t == 0) partials[blockIdx.x] = red[0];
}

__global__ __launch_bounds__(1024) void s_scan_tops_kernel(int* __restrict__ partials)
{
    __shared__ int s[1024];
    int t = threadIdx.x;
    int p0 = partials[2 * t], p1 = partials[2 * t + 1];
    int sum = p0 + p1;
    s[t] = sum;
    __syncthreads();
    for (int off = 1; off < 1024; off <<= 1) {
        int x = (t >= off) ? s[t - off] : 0;
        __syncthreads();
        s[t] += x;
        __syncthreads();
    }
    int excl = s[t] - sum;
    partials[2 * t] = excl;
    partials[2 * t + 1] = excl + p0;
}

__global__ __launch_bounds__(256) void s_scan_final_kernel(
    const int* __restrict__ counts, const int* __restrict__ partials,
    int* __restrict__ offsets, int* __restrict__ cursors)
{
    __shared__ int s[256];
    int t = threadIdx.x;
    int g = blockIdx.x * 256 + t;
    int4 v = ((const int4*)counts)[g];
    int sum = v.x + v.y + v.z + v.w;
    s[t] = sum;
    __syncthreads();
    for (int off = 1; off < 256; off <<= 1) {
        int x = (t >= off) ? s[t - off] : 0;
        __syncthreads();
        s[t] += x;
        __syncthreads();
    }
    int run = partials[blockIdx.x] + s[t] - sum;
    int4 o = make_int4(run, run + v.x, run + v.x + v.y, run + v.x + v.y + v.z);
    ((int4*)offsets)[g] = o;
    ((int4*)cursors)[g] = o;
}

__global__ __launch_bounds__(256) void s_binplace_kernel(
    const float* __restrict__ pos, const float* __restrict__ vel,
    const float* __restrict__ mass, int* __restrict__ cursors,
    float4* __restrict__ records, int n)
{
    int i = blockIdx.x * 256 + threadIdx.x;
    if (i >= n) return;
    float rx = pos[3 * i + 0] * INV_CELL;
    float ry = pos[3 * i + 1] * INV_CELL;
    float rz = pos[3 * i + 2] * INV_CELL;
    int ix = min(max((int)floorf(rx), 0), GRID_DIM - 1);
    int iy = min(max((int)floorf(ry), 0), GRID_DIM - 1);
    int iz = min(max((int)floorf(rz), 0), GRID_DIM - 1);
    int slot = atomicAdd(&cursors[cell_id(ix, iy, iz)], 1);
    records[2 * slot + 0] = make_float4(rx, ry, rz, mass[i]);
    records[2 * slot + 1] = make_float4(vel[3 * i + 0], vel[3 * i + 1],
                                        vel[3 * i + 2], 0.0f);
}

__global__ __launch_bounds__(256) void s_node_gather_kernel(
    const float4* __restrict__ records, const int* __restrict__ offsets,
    const int* __restrict__ cursors, float4* __restrict__ out)
{
    int id = blockIdx.x * 256 + threadIdx.x;
    int gz = id & (GRID_DIM - 1);
    int gx = (id >> 7) & (GRID_DIM - 1);
    int gy = id >> 14;
    float fgx = (float)gx, fgy = (float)gy, fgz = (float)gz;
    float a0 = 0.0f, a1 = 0.0f, a2 = 0.0f, a3 = 0.0f;
    int z0 = max(gz - 1, 0), y0 = max(gy - 1, 0), x0 = max(gx - 1, 0);
    for (int cy = y0; cy <= gy; ++cy) {
        for (int cx = x0; cx <= gx; ++cx) {
            int cb = cx * GRID_DIM + cy * (GRID_DIM * GRID_DIM);
            int beg = offsets[cb + z0];
            int end = cursors[cb + gz];
            for (int p = beg; p < end; ++p) {
                float4 r0 = records[2 * p + 0];
                float4 r1 = records[2 * p + 1];
                float w = (1.0f - fabsf(r0.x - fgx)) *
                          (1.0f - fabsf(r0.y - fgy)) *
                          (1.0f - fabsf(r0.z - fgz));
                float sm = w * r0.w;
                a0 += sm; a1 += sm * r1.x; a2 += sm * r1.y; a3 += sm * r1.z;
            }
        }
    }
    out[id] = make_float4(a0, a1, a2, a3);
}

// ---- last-resort naive scatter --------------------------------------------
__global__ __launch_bounds__(256) void p2g_scatter_kernel(
    const float* __restrict__ pos, const float* __restrict__ vel,
    const float* __restrict__ mass, float* __restrict__ out, int n)
{
    int i = blockIdx.x * blockDim.x + threadIdx.x;
    if (i >= n) return;
    float px = pos[3 * i + 0] * INV_CELL;
    float py = pos[3 * i + 1] * INV_CELL;
    float pz = pos[3 * i + 2] * INV_CELL;
    float bx = floorf(px), by = floorf(py), bz = floorf(pz);
    float fx = px - bx, fy = py - by, fz = pz - bz;
    int ix = (int)bx, iy = (int)by, iz = (int)bz;
    float m = mass[i];
    float vx = vel[3 * i + 0], vy = vel[3 * i + 1], vz = vel[3 * i + 2];
    float wx[2] = { 1.0f - fx, fx }, wy[2] = { 1.0f - fy, fy }, wz[2] = { 1.0f - fz, fz };
    #pragma unroll
    for (int a = 0; a < 2; ++a)
        #pragma unroll
        for (int b = 0; b < 2; ++b)
            #pragma unroll
            for (int c = 0; c < 2; ++c) {
                int h = cell_id(ix + a, iy + b, iz + c);
                bool valid = (h >= 0) && (h < NUM_CELLS);
                int hc = min(max(h, 0), NUM_CELLS - 1);
                float s = valid ? (wx[a] * wy[b] * wz[c]) : 0.0f;
                float sm = s * m;
                float* cell = out + 4 * (size_t)hc;
                atomicAdd(cell + 0, sm);
                atomicAdd(cell + 1, sm * vx);
                atomicAdd(cell + 2, sm * vy);
                atomicAdd(cell + 3, sm * vz);
            }
}

extern "C" void kernel_launch(void* const* d_in, const int* in_sizes, int n_in,
                              void* d_out, int out_size, void* d_ws, size_t ws_size,
                              hipStream_t stream) {
    const float* pos  = (const float*)d_in[0];
    const float* vel  = (const float*)d_in[1];
    const float* mass = (const float*)d_in[2];
    float* out = (float*)d_out;
    int n = in_sizes[2];
    int blocks = (n + 255) / 256;

    // Bucket-path ws: [cursors 8MB][buckets cap*16B*2M][ovf_cnt 256B][ovf_list]
    auto bucket_need = [](int cap) {
        return (size_t)NUM_CELLS * 4 + (size_t)NUM_CELLS * cap * 16
             + 256 + (size_t)OVF_MAX * 4;
    };
    int cap = 0;
    if (ws_size >= bucket_need(4))      cap = 4;
    else if (ws_size >= bucket_need(3)) cap = 3;

    // Sorted-path ws: [counts/cursors 8MB][offsets 8MB][records n*32][partials]
    size_t s_off_offsets  = (size_t)NUM_CELLS * 4;
    size_t s_off_records  = s_off_offsets + (size_t)NUM_CELLS * 4;
    size_t s_off_partials = s_off_records + (size_t)n * 32;
    size_t need_sorted    = s_off_partials + (size_t)SCAN_BLKS * 4;

    if (cap > 0) {
        char* ws = (char*)d_ws;
        unsigned int* cursors = (unsigned int*)ws;
        uint4* buckets = (uint4*)(ws + (size_t)NUM_CELLS * 4);
        int* ovf_cnt   = (int*)(ws + (size_t)NUM_CELLS * 4
                                   + (size_t)NUM_CELLS * cap * 16);
        int* ovf_list  = ovf_cnt + 64;

        hipMemsetAsync(cursors, 0, (size_t)NUM_CELLS * 4, stream);
        hipMemsetAsync(ovf_cnt, 0, 4, stream);
        bucket_place_kernel<<<blocks, 256, 0, stream>>>(
            pos, vel, mass, cursors, buckets, ovf_cnt, ovf_list, cap, n);
        bucket_gather_tiled_kernel<<<NUM_CELLS / 512, 512, 0, stream>>>(
            buckets, cursors, (float4*)out, cap);
        fixup_kernel<<<32, 256, 0, stream>>>(pos, vel, mass, ovf_cnt,
                                             ovf_list, out);
    } else if (ws_size >= need_sorted) {
        char* ws = (char*)d_ws;
        int* counts   = (int*)ws;                    // reused as cursors
        int* offsets  = (int*)(ws + s_off_offsets);
        float4* records = (float4*)(ws + s_off_records);
        int* partials = (int*)(ws + s_off_partials);

        hipMemsetAsync(counts, 0, (size_t)NUM_CELLS * 4, stream);
        s_hist_kernel<<<blocks, 256, 0, stream>>>(pos, counts, n);
        s_scan_partials_kernel<<<SCAN_BLKS, 256, 0, stream>>>(counts, partials);
        s_scan_tops_kernel<<<1, 1024, 0, stream>>>(partials);
        s_scan_final_kernel<<<SCAN_BLKS, 256, 0, stream>>>(counts, partials,
                                                           offsets, counts);
        s_binplace_kernel<<<blocks, 256, 0, stream>>>(pos, vel, mass, counts,
                                                      records, n);
        s_node_gather_kernel<<<NUM_CELLS / 256, 256, 0, stream>>>(
            records, offsets, counts, (float4*)out);
    } else {
        hipMemsetAsync(out, 0, (size_t)out_size * sizeof(float), stream);
        p2g_scatter_kernel<<<blocks, 256, 0, stream>>>(pos, vel, mass, out, n);
    }
}

// Round 2
// 173.274 us; speedup vs baseline: 1.1855x; 1.1179x over previous
//
#include <hip/hip_runtime.h>
#include <hip/hip_fp16.h>

// MPM P2G, per-TILE dense particle lists + LDS-tiled gather (R5).
//
// node[g] = sum over particles in cells {g-1,g}^3 of trilinear w * (m, m*v)
// cell/node id: z + x*128 + y*128*128   (reference get_hash, dim==3)
//
// R1 counters showed BOTH kernels row-cycle-bound on random 64B lines of the
// per-cell bucket array (place: 62.5MB writes @ ~1TB/s, VALUBusy 1.6%;
// gather stage: same lines read back). R5 converts both sides to DENSE:
//   K1 place : tile = 8x8x8 cells (4096 tiles, ~244 particles each).
//              atomicAdd on padded per-tile counter (256KB, L2-resident),
//              append 16B record {fx,fy,fz u16, m,vx,vy,vz fp16, 9-bit
//              cell-local id in spare bits} at consecutive slots ->
//              write lines fill fully (62MB -> ~20MB line traffic).
//   K2 gather: block = 8x8x8 nodes. Stream the 8 covering tiles' lists
//              (coalesced dwordx4, 16MB working set -> L2/L3), LDS-scatter
//              in-halo records into per-cell LDS planes (ds_add cursor),
//              then the verified register accumulate + coalesced store.
//              Per-cell overflow (cnt>MAXCAP, ~1/block) goes straight to
//              an LDS node accumulator -> order-independent, no dedup.
//   K3 fixup : per-tile overflow (statistically never, TCAP=512) exact
//              fp32 atomic scatter after gather.
// Fallback: R3 counting-sort pipeline (verified), then naive scatter.

#define GRID_DIM   128
#define NUM_CELLS  (GRID_DIM * GRID_DIM * GRID_DIM)   // 2,097,152
#define INV_CELL   64.0f
#define OVF_MAX    65536
#define SCAN_BLKS  2048

#define TDIM       16           // tiles per axis (128/8)
#define NTILES     (TDIM * TDIM * TDIM)               // 4096
#define TCAP       512          // records per tile (mean 244, >17 sigma)
#define TCNT_STR   16           // counter pad: one per 64B line
#define MAXCAP     3            // per-cell LDS slots (P(cnt>3) ~ 0.13%)
#define NSC        729          // 9*9*9 staged cells per node tile
#define PLANE      736          // LDS word-plane stride (mult of 32)

__device__ __forceinline__ int cell_id(int ix, int iy, int iz) {
    return iz + ix * GRID_DIM + iy * (GRID_DIM * GRID_DIM);
}

__device__ __forceinline__ unsigned int q16(float f) {
    int q = (int)(f * 65536.0f + 0.5f);
    return (unsigned int)min(q, 65535);
}
__device__ __forceinline__ unsigned int f2h(float f) {
    return (unsigned int)__half_as_ushort(__float2half(f));
}
__device__ __forceinline__ float h2f(unsigned int b) {
    return __half2float(__ushort_as_half((unsigned short)(b & 0xffffu)));
}

// ---- K1: per-tile dense placement -----------------------------------------
__global__ __launch_bounds__(256) void tile_place_kernel(
    const float* __restrict__ pos, const float* __restrict__ vel,
    const float* __restrict__ mass, unsigned int* __restrict__ tile_cnt,
    uint4* __restrict__ lists, int* __restrict__ ovf_cnt,
    int* __restrict__ ovf_list, int n)
{
    int i = blockIdx.x * 256 + threadIdx.x;
    if (i >= n) return;
    float rx = pos[3 * i + 0] * INV_CELL;
    float ry = pos[3 * i + 1] * INV_CELL;
    float rz = pos[3 * i + 2] * INV_CELL;
    float bx = floorf(rx), by = floorf(ry), bz = floorf(rz);
    float fx = rx - bx, fy = ry - by, fz = rz - bz;   // in [0,1)
    int ix = min(max((int)bx, 0), GRID_DIM - 1);
    int iy = min(max((int)by, 0), GRID_DIM - 1);
    int iz = min(max((int)bz, 0), GRID_DIM - 1);
    int tile = (iz >> 3) + ((ix >> 3) << 4) + ((iy >> 3) << 8);
    unsigned int s = atomicAdd(&tile_cnt[tile * TCNT_STR], 1u);
    if (s < (unsigned int)TCAP) {
        unsigned int lid = (unsigned int)((iz & 7) | ((ix & 7) << 3)
                                                   | ((iy & 7) << 6));
        uint4 r;
        r.x = q16(fx) | (q16(fy) << 16);
        r.y = q16(fz) | (f2h(mass[i]) << 16);
        r.z = f2h(vel[3 * i + 0]) | (f2h(vel[3 * i + 1]) << 16);
        r.w = f2h(vel[3 * i + 2]) | (lid << 16);
        lists[(size_t)tile * TCAP + (int)s] = r;
    } else {
        int o = atomicAdd(ovf_cnt, 1);
        if (o < OVF_MAX) ovf_list[o] = i;
    }
}

// ---- K2: tile-streaming node gather ---------------------------------------
// Block = 8x8x8 node tile (512 threads). Stream 8 covering tile lists,
// LDS-scatter in-halo records to per-cell planes, register accumulate.
__global__ __launch_bounds__(512) void tile_gather_kernel(
    const uint4* __restrict__ lists, const unsigned int* __restrict__ tile_cnt,
    float4* __restrict__ out)
{
    __shared__ unsigned int cnt_s[NSC];
    __shared__ unsigned int rec_s[4 * MAXCAP * PLANE];   // 35.3 KB
    __shared__ float nacc[4 * 512];                      // 8 KB overflow acc

    int tid = threadIdx.x;
    // XCD-chunked swizzle (4096 % 8 == 0 -> simple bijective form)
    int swz = (blockIdx.x & 7) * 512 + (blockIdx.x >> 3);
    int bz = swz & 15;
    int bx = (swz >> 4) & 15;
    int by = swz >> 8;
    int g0x = bx * 8, g0y = by * 8, g0z = bz * 8;

    for (int sc = tid; sc < NSC; sc += 512) cnt_s[sc] = 0;
    nacc[tid] = 0.0f; nacc[512 + tid] = 0.0f;
    nacc[1024 + tid] = 0.0f; nacc[1536 + tid] = 0.0f;
    __syncthreads();

    // ---- stage: stream records from the 8 covering tiles ------------------
    #pragma unroll
    for (int dty = -1; dty <= 0; ++dty)
    #pragma unroll
    for (int dtx = -1; dtx <= 0; ++dtx)
    #pragma unroll
    for (int dtz = -1; dtz <= 0; ++dtz) {
        int tx_ = bx + dtx, ty_ = by + dty, tz_ = bz + dtz;
        if ((tx_ < 0) || (ty_ < 0) || (tz_ < 0)) continue;
        int tile = tz_ + (tx_ << 4) + (ty_ << 8);
        int cnt = (int)min(tile_cnt[tile * TCNT_STR], (unsigned int)TCAP);
        const uint4* base = lists + (size_t)tile * TCAP;
        int c0x = tx_ * 8, c0y = ty_ * 8, c0z = tz_ * 8;
        for (int r = tid; r < cnt; r += 512) {
            uint4 rec = base[r];
            unsigned int lid = rec.w >> 16;
            int cz = c0z + (int)(lid & 7u);
            int cx = c0x + (int)((lid >> 3) & 7u);
            int cy = c0y + (int)(lid >> 6);
            int uz = cz - (g0z - 1), ux = cx - (g0x - 1), uy = cy - (g0y - 1);
            if (((unsigned)uz < 9u) & ((unsigned)ux < 9u) & ((unsigned)uy < 9u)) {
                int sc = uy * 81 + ux * 9 + uz;
                unsigned int j = atomicAdd(&cnt_s[sc], 1u);
                if (j < MAXCAP) {
                    rec_s[(0 * MAXCAP + j) * PLANE + sc] = rec.x;
                    rec_s[(1 * MAXCAP + j) * PLANE + sc] = rec.y;
                    rec_s[(2 * MAXCAP + j) * PLANE + sc] = rec.z;
                    rec_s[(3 * MAXCAP + j) * PLANE + sc] = rec.w;
                } else {
                    // rare: accumulate directly into LDS node accumulators
                    float fx = (float)(rec.x & 0xffffu) * (1.0f / 65536.0f);
                    float fy = (float)(rec.x >> 16)     * (1.0f / 65536.0f);
                    float fz = (float)(rec.y & 0xffffu) * (1.0f / 65536.0f);
                    float m  = h2f(rec.y >> 16);
                    float vx = h2f(rec.z), vy = h2f(rec.z >> 16), vz = h2f(rec.w);
                    #pragma unroll
                    for (int oy = 0; oy < 2; ++oy)
                    #pragma unroll
                    for (int ox = 0; ox < 2; ++ox)
                    #pragma unroll
                    for (int oz = 0; oz < 2; ++oz) {
                        int pz = cz + oz - g0z;
                        int px = cx + ox - g0x;
                        int py = cy + oy - g0y;
                        if (((unsigned)pz < 8u) & ((unsigned)px < 8u) &
                            ((unsigned)py < 8u)) {
                            float w = (ox ? fx : 1.0f - fx) *
                                      (oy ? fy : 1.0f - fy) *
                                      (oz ? fz : 1.0f - fz);
                            float sm = w * m;
                            int idx = py * 64 + px * 8 + pz;
                            atomicAdd(&nacc[0 * 512 + idx], sm);
                            atomicAdd(&nacc[1 * 512 + idx], sm * vx);
                            atomicAdd(&nacc[2 * 512 + idx], sm * vy);
                            atomicAdd(&nacc[3 * 512 + idx], sm * vz);
                        }
                    }
                }
            }
        }
    }
    __syncthreads();

    // ---- accumulate: thread owns node (tx,ty,tz) = tid --------------------
    int tz = tid & 7, tx = (tid >> 3) & 7, ty = tid >> 6;
    float a0 = nacc[tid], a1 = nacc[512 + tid];
    float a2 = nacc[1024 + tid], a3 = nacc[1536 + tid];

    #pragma unroll
    for (int dy = 0; dy < 2; ++dy) {
        #pragma unroll
        for (int dx = 0; dx < 2; ++dx) {
            int scb = (ty + dy) * 81 + (tx + dx) * 9 + tz;
            #pragma unroll
            for (int dz = 0; dz < 2; ++dz) {
                int sc = scb + dz;
                int cnt = min((int)cnt_s[sc], MAXCAP);
                for (int j = 0; j < cnt; ++j) {
                    unsigned r0 = rec_s[(0 * MAXCAP + j) * PLANE + sc];
                    unsigned r1 = rec_s[(1 * MAXCAP + j) * PLANE + sc];
                    unsigned r2 = rec_s[(2 * MAXCAP + j) * PLANE + sc];
                    unsigned r3 = rec_s[(3 * MAXCAP + j) * PLANE + sc];
                    float fx = (float)(r0 & 0xffffu) * (1.0f / 65536.0f);
                    float fy = (float)(r0 >> 16)     * (1.0f / 65536.0f);
                    float fz = (float)(r1 & 0xffffu) * (1.0f / 65536.0f);
                    // dx==1 -> staged cell == node's own cell -> (1-frac)
                    float wx = dx ? (1.0f - fx) : fx;
                    float wy = dy ? (1.0f - fy) : fy;
                    float wz = dz ? (1.0f - fz) : fz;
                    float sm = wx * wy * wz * h2f(r1 >> 16);
                    a0 += sm;
                    a1 += sm * h2f(r2);
                    a2 += sm * h2f(r2 >> 16);
                    a3 += sm * h2f(r3);
                }
            }
        }
    }
    int id = (g0z + tz) + (g0x + tx) * GRID_DIM
           + (g0y + ty) * (GRID_DIM * GRID_DIM);
    out[id] = make_float4(a0, a1, a2, a3);
}

// ---- K3: tile-overflow fixup (exact fp32, statistically never) ------------
__global__ __launch_bounds__(256) void fixup_kernel(
    const float* __restrict__ pos, const float* __restrict__ vel,
    const float* __restrict__ mass, const int* __restrict__ ovf_cnt,
    const int* __restrict__ ovf_list, float* __restrict__ out)
{
    int total = min(*ovf_cnt, OVF_MAX);
    for (int k = blockIdx.x * 256 + threadIdx.x; k < total; k += gridDim.x * 256) {
        int i = ovf_list[k];
        float px = pos[3 * i + 0] * INV_CELL;
        float py = pos[3 * i + 1] * INV_CELL;
        float pz = pos[3 * i + 2] * INV_CELL;
        float bx = floorf(px), by = floorf(py), bz = floorf(pz);
        float fx = px - bx, fy = py - by, fz = pz - bz;
        int ix = (int)bx, iy = (int)by, iz = (int)bz;
        float m = mass[i];
        float vx = vel[3 * i + 0], vy = vel[3 * i + 1], vz = vel[3 * i + 2];
        float wx[2] = { 1.0f - fx, fx }, wy[2] = { 1.0f - fy, fy }, wz[2] = { 1.0f - fz, fz };
        #pragma unroll
        for (int a = 0; a < 2; ++a)
            #pragma unroll
            for (int b = 0; b < 2; ++b)
                #pragma unroll
                for (int c = 0; c < 2; ++c) {
                    int h = cell_id(ix + a, iy + b, iz + c);
                    bool valid = (h >= 0) && (h < NUM_CELLS);
                    int hc = min(max(h, 0), NUM_CELLS - 1);
                    float s = valid ? (wx[a] * wy[b] * wz[c]) : 0.0f;
                    float sm = s * m;
                    float* cell = out + 4 * (size_t)hc;
                    atomicAdd(cell + 0, sm);
                    atomicAdd(cell + 1, sm * vx);
                    atomicAdd(cell + 2, sm * vy);
                    atomicAdd(cell + 3, sm * vz);
                }
    }
}

// ======== fallback: R3 counting-sort pipeline (verified) ===================
__global__ __launch_bounds__(256) void s_hist_kernel(
    const float* __restrict__ pos, int* __restrict__ counts, int n)
{
    int i = blockIdx.x * 256 + threadIdx.x;
    if (i >= n) return;
    int ix = min(max((int)floorf(pos[3 * i + 0] * INV_CELL), 0), GRID_DIM - 1);
    int iy = min(max((int)floorf(pos[3 * i + 1] * INV_CELL), 0), GRID_DIM - 1);
    int iz = min(max((int)floorf(pos[3 * i + 2] * INV_CELL), 0), GRID_DIM - 1);
    atomicAdd(&counts[cell_id(ix, iy, iz)], 1);
}

__global__ __launch_bounds__(256) void s_scan_partials_kernel(
    const int* __restrict__ counts, int* __restrict__ partials)
{
    __shared__ int red[256];
    int t = threadIdx.x;
    int4 v = ((const int4*)counts)[blockIdx.x * 256 + t];
    red[t] = v.x + v.y + v.z + v.w;
    __syncthreads();
    for (int off = 128; off > 0; off >>= 1) {
        if (t < off) red[t] += red[t + off];
        __syncthreads();
    }
    if (t == 0) partials[blockIdx.x] = red[0];
}

__global__ __launch_bounds__(1024) void s_scan_tops_kernel(int* __restrict__ partials)
{
    __shared__ int s[1024];
    int t = threadIdx.x;
    int p0 = partials[2 * t], p1 = partials[2 * t + 1];
    int sum = p0 + p1;
    s[t] = sum;
    __syncthreads();
    for (int off = 1; off < 1024; off <<= 1) {
        int x = (t >= off) ? s[t - off] : 0;
        __syncthreads();
        s[t] += x;
        __syncthreads();
    }
    int excl = s[t] - sum;
    partials[2 * t] = excl;
    partials[2 * t + 1] = excl + p0;
}

__global__ __launch_bounds__(256) void s_scan_final_kernel(
    const int* __restrict__ counts, const int* __restrict__ partials,
    int* __restrict__ offsets, int* __restrict__ cursors)
{
    __shared__ int s[256];
    int t = threadIdx.x;
    int g = blockIdx.x * 256 + t;
    int4 v = ((const int4*)counts)[g];
    int sum = v.x + v.y + v.z + v.w;
    s[t] = sum;
    __syncthreads();
    for (int off = 1; off < 256; off <<= 1) {
        int x = (t >= off) ? s[t - off] : 0;
        __syncthreads();
        s[t] += x;
        __syncthreads();
    }
    int run = partials[blockIdx.x] + s[t] - sum;
    int4 o = make_int4(run, run + v.x, run + v.x + v.y, run + v.x + v.y + v.z);
    ((int4*)offsets)[g] = o;
    ((int4*)cursors)[g] = o;
}

__global__ __launch_bounds__(256) void s_binplace_kernel(
    const float* __restrict__ pos, const float* __restrict__ vel,
    const float* __restrict__ mass, int* __restrict__ cursors,
    float4* __restrict__ records, int n)
{
    int i = blockIdx.x * 256 + threadIdx.x;
    if (i >= n) return;
    float rx = pos[3 * i + 0] * INV_CELL;
    float ry = pos[3 * i + 1] * INV_CELL;
    float rz = pos[3 * i + 2] * INV_CELL;
    int ix = min(max((int)floorf(rx), 0), GRID_DIM - 1);
    int iy = min(max((int)floorf(ry), 0), GRID_DIM - 1);
    int iz = min(max((int)floorf(rz), 0), GRID_DIM - 1);
    int slot = atomicAdd(&cursors[cell_id(ix, iy, iz)], 1);
    records[2 * slot + 0] = make_float4(rx, ry, rz, mass[i]);
    records[2 * slot + 1] = make_float4(vel[3 * i + 0], vel[3 * i + 1],
                                        vel[3 * i + 2], 0.0f);
}

__global__ __launch_bounds__(256) void s_node_gather_kernel(
    const float4* __restrict__ records, const int* __restrict__ offsets,
    const int* __restrict__ cursors, float4* __restrict__ out)
{
    int id = blockIdx.x * 256 + threadIdx.x;
    int gz = id & (GRID_DIM - 1);
    int gx = (id >> 7) & (GRID_DIM - 1);
    int gy = id >> 14;
    float fgx = (float)gx, fgy = (float)gy, fgz = (float)gz;
    float a0 = 0.0f, a1 = 0.0f, a2 = 0.0f, a3 = 0.0f;
    int z0 = max(gz - 1, 0), y0 = max(gy - 1, 0), x0 = max(gx - 1, 0);
    for (int cy = y0; cy <= gy; ++cy) {
        for (int cx = x0; cx <= gx; ++cx) {
            int cb = cx * GRID_DIM + cy * (GRID_DIM * GRID_DIM);
            int beg = offsets[cb + z0];
            int end = cursors[cb + gz];
            for (int p = beg; p < end; ++p) {
                float4 r0 = records[2 * p + 0];
                float4 r1 = records[2 * p + 1];
                float w = (1.0f - fabsf(r0.x - fgx)) *
                          (1.0f - fabsf(r0.y - fgy)) *
                          (1.0f - fabsf(r0.z - fgz));
                float sm = w * r0.w;
                a0 += sm; a1 += sm * r1.x; a2 += sm * r1.y; a3 += sm * r1.z;
            }
        }
    }
    out[id] = make_float4(a0, a1, a2, a3);
}

// ---- last-resort naive scatter --------------------------------------------
__global__ __launch_bounds__(256) void p2g_scatter_kernel(
    const float* __restrict__ pos, const float* __restrict__ vel,
    const float* __restrict__ mass, float* __restrict__ out, int n)
{
    int i = blockIdx.x * blockDim.x + threadIdx.x;
    if (i >= n) return;
    float px = pos[3 * i + 0] * INV_CELL;
    float py = pos[3 * i + 1] * INV_CELL;
    float pz = pos[3 * i + 2] * INV_CELL;
    float bx = floorf(px), by = floorf(py), bz = floorf(pz);
    float fx = px - bx, fy = py - by, fz = pz - bz;
    int ix = (int)bx, iy = (int)by, iz = (int)bz;
    float m = mass[i];
    float vx = vel[3 * i + 0], vy = vel[3 * i + 1], vz = vel[3 * i + 2];
    float wx[2] = { 1.0f - fx, fx }, wy[2] = { 1.0f - fy, fy }, wz[2] = { 1.0f - fz, fz };
    #pragma unroll
    for (int a = 0; a < 2; ++a)
        #pragma unroll
        for (int b = 0; b < 2; ++b)
            #pragma unroll
            for (int c = 0; c < 2; ++c) {
                int h = cell_id(ix + a, iy + b, iz + c);
                bool valid = (h >= 0) && (h < NUM_CELLS);
                int hc = min(max(h, 0), NUM_CELLS - 1);
                float s = valid ? (wx[a] * wy[b] * wz[c]) : 0.0f;
                float sm = s * m;
                float* cell = out + 4 * (size_t)hc;
                atomicAdd(cell + 0, sm);
                atomicAdd(cell + 1, sm * vx);
                atomicAdd(cell + 2, sm * vy);
                atomicAdd(cell + 3, sm * vz);
            }
}

extern "C" void kernel_launch(void* const* d_in, const int* in_sizes, int n_in,
                              void* d_out, int out_size, void* d_ws, size_t ws_size,
                              hipStream_t stream) {
    const float* pos  = (const float*)d_in[0];
    const float* vel  = (const float*)d_in[1];
    const float* mass = (const float*)d_in[2];
    float* out = (float*)d_out;
    int n = in_sizes[2];
    int blocks = (n + 255) / 256;

    // Tile-path ws: [tile_cnt 256KB][lists 32MB][ovf_cnt 256B][ovf_list 256KB]
    size_t t_off_lists = (size_t)NTILES * TCNT_STR * 4;            // 256 KB
    size_t t_off_ovf   = t_off_lists + (size_t)NTILES * TCAP * 16; // +32 MB
    size_t need_tiles  = t_off_ovf + 256 + (size_t)OVF_MAX * 4;

    // Sorted-path ws: [counts/cursors 8MB][offsets 8MB][records n*32][partials]
    size_t s_off_offsets  = (size_t)NUM_CELLS * 4;
    size_t s_off_records  = s_off_offsets + (size_t)NUM_CELLS * 4;
    size_t s_off_partials = s_off_records + (size_t)n * 32;
    size_t need_sorted    = s_off_partials + (size_t)SCAN_BLKS * 4;

    if (ws_size >= need_tiles) {
        char* ws = (char*)d_ws;
        unsigned int* tile_cnt = (unsigned int*)ws;
        uint4* lists  = (uint4*)(ws + t_off_lists);
        int* ovf_cnt  = (int*)(ws + t_off_ovf);
        int* ovf_list = ovf_cnt + 64;

        hipMemsetAsync(tile_cnt, 0, t_off_lists, stream);
        hipMemsetAsync(ovf_cnt, 0, 4, stream);
        tile_place_kernel<<<blocks, 256, 0, stream>>>(
            pos, vel, mass, tile_cnt, lists, ovf_cnt, ovf_list, n);
        tile_gather_kernel<<<NTILES, 512, 0, stream>>>(
            lists, tile_cnt, (float4*)out);
        fixup_kernel<<<32, 256, 0, stream>>>(pos, vel, mass, ovf_cnt,
                                             ovf_list, out);
    } else if (ws_size >= need_sorted) {
        char* ws = (char*)d_ws;
        int* counts   = (int*)ws;                    // reused as cursors
        int* offsets  = (int*)(ws + s_off_offsets);
        float4* records = (float4*)(ws + s_off_records);
        int* partials = (int*)(ws + s_off_partials);

        hipMemsetAsync(counts, 0, (size_t)NUM_CELLS * 4, stream);
        s_hist_kernel<<<blocks, 256, 0, stream>>>(pos, counts, n);
        s_scan_partials_kernel<<<SCAN_BLKS, 256, 0, stream>>>(counts, partials);
        s_scan_tops_kernel<<<1, 1024, 0, stream>>>(partials);
        s_scan_final_kernel<<<SCAN_BLKS, 256, 0, stream>>>(counts, partials,
                                                           offsets, counts);
        s_binplace_kernel<<<blocks, 256, 0, stream>>>(pos, vel, mass, counts,
                                                      records, n);
        s_node_gather_kernel<<<NUM_CELLS / 256, 256, 0, stream>>>(
            records, offsets, counts, (float4*)out);
    } else {
        hipMemsetAsync(out, 0, (size_t)out_size * sizeof(float), stream);
        p2g_scatter_kernel<<<blocks, 256, 0, stream>>>(pos, vel, mass, out, n);
    }
}